// Round 9
// baseline (277.583 us; speedup 1.0000x reference)
//
#include <hip/hip_runtime.h>
#include <math.h>

#define BB 16
#define TT 24
#define NN 128
#define DD 64
#define PTOT (BB * TT * NN)   // 49152 positions
#define P64  (PTOT * 64)      // elements per (B,T,N,64) buffer

typedef __attribute__((ext_vector_type(8))) short bf16x8;
typedef __attribute__((ext_vector_type(4))) float f32x4;

__device__ __forceinline__ unsigned short f2bf(float f) {
    unsigned u = __builtin_bit_cast(unsigned, f);
    u = (u + 0x7fffu + ((u >> 16) & 1u)) >> 16;   // round-to-nearest-even
    return (unsigned short)u;
}
__device__ __forceinline__ void unpack8(uint4 u, float* f) {
    f[0] = __builtin_bit_cast(float, u.x << 16);
    f[1] = __builtin_bit_cast(float, u.x & 0xFFFF0000u);
    f[2] = __builtin_bit_cast(float, u.y << 16);
    f[3] = __builtin_bit_cast(float, u.y & 0xFFFF0000u);
    f[4] = __builtin_bit_cast(float, u.z << 16);
    f[5] = __builtin_bit_cast(float, u.z & 0xFFFF0000u);
    f[6] = __builtin_bit_cast(float, u.w << 16);
    f[7] = __builtin_bit_cast(float, u.w & 0xFFFF0000u);
}
__device__ __forceinline__ uint4 pack8(const float* f) {
    uint4 o;
    o.x = (unsigned)f2bf(f[0]) | ((unsigned)f2bf(f[1]) << 16);
    o.y = (unsigned)f2bf(f[2]) | ((unsigned)f2bf(f[3]) << 16);
    o.z = (unsigned)f2bf(f[4]) | ((unsigned)f2bf(f[5]) << 16);
    o.w = (unsigned)f2bf(f[6]) | ((unsigned)f2bf(f[7]) << 16);
    return o;
}

// ---------------------------------------------------------------------------
// Kernel 0: combined weight prep.
// blocks 0..287: 6 proj weights (192x64) -> bf16 [j][n][k]  (Wt)
// blocks 288..415: 8 epi weights (64x64) -> bf16 [mat][n][k] (Wt8)
// ---------------------------------------------------------------------------
__global__ __launch_bounds__(256) void wprep_all(
    const float* __restrict__ W0, const float* __restrict__ W1,
    const float* __restrict__ W2, const float* __restrict__ W3,
    const float* __restrict__ W4, const float* __restrict__ W5,
    const float* __restrict__ E0, const float* __restrict__ E1,
    const float* __restrict__ E2, const float* __restrict__ E3,
    const float* __restrict__ E4, const float* __restrict__ E5,
    const float* __restrict__ E6, const float* __restrict__ E7,
    unsigned short* __restrict__ Wt, unsigned short* __restrict__ Wt8)
{
    const int bid = blockIdx.x;
    if (bid < 288) {
        const float* Ws[6] = {W0, W1, W2, W3, W4, W5};
        const int e = bid * 256 + threadIdx.x;          // < 73728
        const int j = e / 12288;
        const int r = e % 12288;
        const int k = r / 64;
        const int n = r % 64;
        Wt[j * 12288 + n * 192 + k] = f2bf(Ws[j][k * 64 + n]);
    } else {
        const float* Es[8] = {E0, E1, E2, E3, E4, E5, E6, E7};
        const int e = (bid - 288) * 256 + threadIdx.x;  // < 32768
        const int mat = e >> 12;
        const int r = e & 4095;
        const int k = r >> 6;
        const int n = r & 63;
        Wt8[mat * 4096 + n * 64 + k] = f2bf(Es[mat][k * 64 + n]);
    }
}

// ---------------------------------------------------------------------------
// Kernel 1: FUSED 6-way QKV projection + spatial attention, 512 threads.
// One block per (b,t): 128 positions, 8 waves.
// GEMM phase (BARRIER-FREE): wave w owns positions w*16..w*16+15.
//   XE B-fragments loaded DIRECTLY from global in MFMA fragment order
//   (lane(l16,quad) holds XE[pos=w*16+l16][kc*32+quad*8 .. +7]).
//   Weight A-frags streamed from L2-hot Wt per (mat, mtile).
//   Per mat: 4 mtile x 6 kc MFMAs -> lane holds (ch=mtile*16+quad*4..+3,
//   pos=w*16+l16); spatial mats 0..2 -> swizzled bf16 LDS, temporal 3..5 ->
//   global bf16.  Swizzle g=(mtile+(quad>>1)*4+pos)&7: exact 2-way write
//   aliasing (free).
// Attention phase: wave = head; k/v LDS reads are wave-broadcast; lane owns
//   2 query rows.  Single-pass softmax w/o max (inputs relu'd, dots bounded).
// LDS: 3*128*64*2 = 49152 B -> 2 blocks/CU, all 384 blocks resident.
// ---------------------------------------------------------------------------
__global__ __launch_bounds__(512, 4) void fused_sattn(
    const float* __restrict__ X, const float* __restrict__ TLE,
    const unsigned short* __restrict__ Wt,   // [6][64][192] bf16
    const float* __restrict__ b0, const float* __restrict__ b1,
    const float* __restrict__ b2, const float* __restrict__ b3,
    const float* __restrict__ b4, const float* __restrict__ b5,
    unsigned short* __restrict__ qt, unsigned short* __restrict__ kt,
    unsigned short* __restrict__ vt,
    unsigned short* __restrict__ HS)
{
    __shared__ __align__(16) unsigned short qq[128 * 64];
    __shared__ __align__(16) unsigned short kk[128 * 64];
    __shared__ __align__(16) unsigned short vv[128 * 64];
    const int tid = threadIdx.x;
    const long p0 = (long)blockIdx.x * 128;
    const int w = tid >> 6, l = tid & 63, quad = l >> 4, l16 = l & 15;

    // ---- load B fragments direct from global (fragment order) ----
    const int pos  = w * 16 + l16;
    const long prow = p0 + pos;
    bf16x8 Bf[6];
    #pragma unroll
    for (int kc = 0; kc < 6; ++kc) {
        const int k0 = kc * 32 + quad * 8;
        const float* src = (k0 < 64) ? X + prow * 64 + k0
                                     : TLE + prow * 128 + (k0 - 64);
        const float4 a = *reinterpret_cast<const float4*>(src);
        const float4 b = *reinterpret_cast<const float4*>(src + 4);
        bf16x8 f;
        f[0] = (short)f2bf(a.x); f[1] = (short)f2bf(a.y);
        f[2] = (short)f2bf(a.z); f[3] = (short)f2bf(a.w);
        f[4] = (short)f2bf(b.x); f[5] = (short)f2bf(b.y);
        f[6] = (short)f2bf(b.z); f[7] = (short)f2bf(b.w);
        Bf[kc] = f;
    }

    const float* bias_p[6] = {b0, b1, b2, b3, b4, b5};
    unsigned short* bufS[3] = {qq, kk, vv};
    unsigned short* dstT[3] = {qt, kt, vt};
    const int g_base = (quad >> 1) * 4 + pos;     // + mtile, &7 below
    const int sub    = (quad & 1) * 4;

    #pragma unroll
    for (int mat = 0; mat < 6; ++mat) {
        const unsigned short* wp = Wt + mat * 12288 + l16 * 192 + quad * 8;
        #pragma unroll
        for (int mtile = 0; mtile < 4; ++mtile) {
            f32x4 acc = (f32x4){0.f, 0.f, 0.f, 0.f};
            const unsigned short* wpt = wp + mtile * 16 * 192;
            #pragma unroll
            for (int kc = 0; kc < 6; ++kc) {
                const bf16x8 wf = *reinterpret_cast<const bf16x8*>(wpt + kc * 32);
                acc = __builtin_amdgcn_mfma_f32_16x16x32_bf16(wf, Bf[kc], acc, 0, 0, 0);
            }
            const float4 b4 = *reinterpret_cast<const float4*>(
                &bias_p[mat][mtile * 16 + quad * 4]);
            ushort4 pk;
            pk.x = f2bf(fmaxf(acc[0] + b4.x, 0.f));
            pk.y = f2bf(fmaxf(acc[1] + b4.y, 0.f));
            pk.z = f2bf(fmaxf(acc[2] + b4.z, 0.f));
            pk.w = f2bf(fmaxf(acc[3] + b4.w, 0.f));
            if (mat < 3) {
                const int g = (mtile + g_base) & 7;
                *reinterpret_cast<ushort4*>(
                    &bufS[mat][pos * 64 + g * 8 + sub]) = pk;
            } else {
                *reinterpret_cast<ushort4*>(
                    &dstT[mat - 3][prow * 64 + mtile * 16 + quad * 4]) = pk;
            }
        }
    }
    __syncthreads();

    // ---------------- attention phase: wave = head ----------------
    const int h  = w;
    const int ph = (h >> 1) | ((h & 1) << 2);     // storage perm of chunk id
    const float scale = 0.35355339059327373f;     // 1/sqrt(8)

    float q[2][8];
    #pragma unroll
    for (int r2 = 0; r2 < 2; ++r2) {
        const int row = l + r2 * 64;
        const uint4 qu = *reinterpret_cast<const uint4*>(
            &qq[row * 64 + (((ph + row) & 7) << 3)]);
        float qf[8]; unpack8(qu, qf);
        #pragma unroll
        for (int d = 0; d < 8; ++d) q[r2][d] = qf[d] * scale;
    }

    float sum[2] = {0.f, 0.f};
    float acc[2][8];
    #pragma unroll
    for (int r2 = 0; r2 < 2; ++r2)
        #pragma unroll
        for (int d = 0; d < 8; ++d) acc[r2][d] = 0.f;

    for (int m = 0; m < NN; ++m) {
        const int co = ((ph + m) & 7) << 3;       // wave-uniform -> broadcast
        const uint4 ku = *reinterpret_cast<const uint4*>(&kk[m * 64 + co]);
        const uint4 vu = *reinterpret_cast<const uint4*>(&vv[m * 64 + co]);
        float kf[8], vf[8];
        unpack8(ku, kf); unpack8(vu, vf);
        #pragma unroll
        for (int r2 = 0; r2 < 2; ++r2) {
            float s = q[r2][0] * kf[0];
            #pragma unroll
            for (int d = 1; d < 8; ++d) s = fmaf(q[r2][d], kf[d], s);
            const float e = __expf(s);
            sum[r2] += e;
            #pragma unroll
            for (int d = 0; d < 8; ++d) acc[r2][d] = fmaf(e, vf[d], acc[r2][d]);
        }
    }

    #pragma unroll
    for (int r2 = 0; r2 < 2; ++r2) {
        const int row = l + r2 * 64;
        const float inv = 1.0f / sum[r2];
        float o[8];
        #pragma unroll
        for (int d = 0; d < 8; ++d) o[d] = acc[r2][d] * inv;
        *reinterpret_cast<uint4*>(&HS[(p0 + row) * 64 + h * 8]) = pack8(o);
    }
}

// ---------------------------------------------------------------------------
// Kernel 2: temporal attention (causal + key padding), bf16 I/O.
// One block per (b, n); 192 threads = (head h, query time i).
// ---------------------------------------------------------------------------
__global__ __launch_bounds__(192) void tattn_kernel(
    const unsigned short* __restrict__ Q, const unsigned short* __restrict__ Kb,
    const unsigned short* __restrict__ V, const int* __restrict__ kpm,
    unsigned short* __restrict__ O)
{
    __shared__ float kk[8][TT][8];
    __shared__ float vv[8][TT][8];
    const int tid = threadIdx.x;
    const int n = blockIdx.x & (NN - 1);
    const int b = blockIdx.x >> 7;

    {   // staging: thread = (head hs, time j)
        const int hs = tid / TT;
        const int j  = tid % TT;
        const long g = (((long)(b * TT + j)) * NN + n) * 64 + hs * 8;
        uint4 ku = *reinterpret_cast<const uint4*>(&Kb[g]);
        uint4 vu = *reinterpret_cast<const uint4*>(&V[g]);
        float kf[8], vf[8];
        unpack8(ku, kf); unpack8(vu, vf);
        #pragma unroll
        for (int d = 0; d < 8; ++d) { kk[hs][j][d] = kf[d]; vv[hs][j][d] = vf[d]; }
    }

    const int h = tid / TT;
    const int i = tid % TT;
    const long qb = (((long)(b * TT + i)) * NN + n) * 64 + h * 8;
    float q[8];
    {
        uint4 qu = *reinterpret_cast<const uint4*>(&Q[qb]);
        unpack8(qu, q);
    }
    __syncthreads();

    const int kp = kpm[b];
    const float scale = 0.35355339059327373f;

    float s[TT];
    #pragma unroll
    for (int j = 0; j < TT; ++j) {
        float t = 0.0f;
        #pragma unroll
        for (int d = 0; d < 8; ++d) t = fmaf(q[d], kk[h][j][d], t);
        s[j] = (j <= i && j < kp) ? t * scale : -INFINITY;
    }
    float mx = -INFINITY;
    #pragma unroll
    for (int j = 0; j < TT; ++j) mx = fmaxf(mx, s[j]);

    float sum = 0.0f;
    float acc[8];
    #pragma unroll
    for (int d = 0; d < 8; ++d) acc[d] = 0.0f;
    #pragma unroll
    for (int j = 0; j < TT; ++j) {
        const float e = __expf(s[j] - mx);  // masked -> exp(-inf)=0
        sum += e;
        #pragma unroll
        for (int d = 0; d < 8; ++d) acc[d] = fmaf(e, vv[h][j][d], acc[d]);
    }
    const float inv = 1.0f / sum;
    float o[8];
    #pragma unroll
    for (int d = 0; d < 8; ++d) o[d] = acc[d] * inv;
    *reinterpret_cast<uint4*>(&O[qb]) = pack8(o);
}

// ---------------------------------------------------------------------------
// Kernel 3: epilogue via bf16 MFMA, swapped operands.
// Block = 256 thr (4 waves), 64-position tile.  Grid = PTOT/64 = 768.
// ---------------------------------------------------------------------------
__global__ __launch_bounds__(256) void epi_kernel(
    const float* __restrict__ X,
    const unsigned short* __restrict__ HSb, const unsigned short* __restrict__ HTb,
    const unsigned short* __restrict__ Wt8,  // [8][64][64] bf16
    const float* __restrict__ sbo1, const float* __restrict__ sbo2,
    const float* __restrict__ tbo1, const float* __restrict__ tbo2,
    const float* __restrict__ bxt,
    const float* __restrict__ bh1, const float* __restrict__ bh2,
    float* __restrict__ out)
{
    constexpr int RS = 72;
    __shared__ __align__(16) unsigned short bufA[64][RS], bufB[64][RS], bufC[64][RS];
    const int tid = threadIdx.x;
    const long p0 = (long)blockIdx.x * 64;
    const int w = tid >> 6, l = tid & 63, quad = l >> 4, l16 = l & 15;
    const int chBase = w * 16 + quad * 4;

    #pragma unroll
    for (int i = 0; i < 4; ++i) {
        const int idx = tid + i * 256;      // < 1024
        const int m = idx >> 4;
        const int c = (idx & 15) * 4;
        *reinterpret_cast<ushort4*>(&bufA[m][c]) =
            *reinterpret_cast<const ushort4*>(&HSb[(p0 + m) * 64 + c]);
        *reinterpret_cast<ushort4*>(&bufC[m][c]) =
            *reinterpret_cast<const ushort4*>(&HTb[(p0 + m) * 64 + c]);
    }
    __syncthreads();

    auto gemm = [&](const unsigned short (*in)[RS], int mat,
                    const float* __restrict__ bias, f32x4* accO) {
        bf16x8 af[2];
        #pragma unroll
        for (int kc = 0; kc < 2; ++kc)
            af[kc] = *reinterpret_cast<const bf16x8*>(
                &Wt8[mat * 4096 + (w * 16 + l16) * 64 + kc * 32 + quad * 8]);
        const float4 b4 = *reinterpret_cast<const float4*>(&bias[chBase]);
        #pragma unroll
        for (int pt = 0; pt < 4; ++pt) {
            f32x4 acc = (f32x4){0.f, 0.f, 0.f, 0.f};
            #pragma unroll
            for (int kc = 0; kc < 2; ++kc) {
                bf16x8 bf = *reinterpret_cast<const bf16x8*>(
                    &in[pt * 16 + l16][kc * 32 + quad * 8]);
                acc = __builtin_amdgcn_mfma_f32_16x16x32_bf16(af[kc], bf, acc, 0, 0, 0);
            }
            acc[0] += b4.x; acc[1] += b4.y; acc[2] += b4.z; acc[3] += b4.w;
            accO[pt] = acc;
        }
    };

    auto writeBuf = [&](unsigned short (*dst)[RS], const f32x4* v, bool relu) {
        #pragma unroll
        for (int pt = 0; pt < 4; ++pt) {
            float a0 = v[pt][0], a1 = v[pt][1], a2 = v[pt][2], a3 = v[pt][3];
            if (relu) { a0 = fmaxf(a0, 0.f); a1 = fmaxf(a1, 0.f);
                        a2 = fmaxf(a2, 0.f); a3 = fmaxf(a3, 0.f); }
            ushort4 pk; pk.x = f2bf(a0); pk.y = f2bf(a1); pk.z = f2bf(a2); pk.w = f2bf(a3);
            *reinterpret_cast<ushort4*>(&dst[pt * 16 + l16][chBase]) = pk;
        }
    };

    f32x4 t[4], HSr[4], HTr[4];

    gemm(bufA, 0, sbo1, t);                 // HS1 = relu(HS@sWo1+b)
    __syncthreads();
    writeBuf(bufB, t, true);
    __syncthreads();

    gemm(bufB, 1, sbo2, HSr);               // HS2 (fp32 regs)
    __syncthreads();
    writeBuf(bufA, HSr, false);
    __syncthreads();

    gemm(bufC, 2, tbo1, t);                 // HT1 = relu(HT@tWo1+b)
    __syncthreads();
    writeBuf(bufB, t, true);
    __syncthreads();

    gemm(bufB, 3, tbo2, HTr);               // HT2 (fp32 regs)
    __syncthreads();
    writeBuf(bufC, HTr, false);
    __syncthreads();

    // ---- gate ----
    {
        bf16x8 afS[2], afT[2];
        #pragma unroll
        for (int kc = 0; kc < 2; ++kc) {
            afS[kc] = *reinterpret_cast<const bf16x8*>(
                &Wt8[4 * 4096 + (w * 16 + l16) * 64 + kc * 32 + quad * 8]);
            afT[kc] = *reinterpret_cast<const bf16x8*>(
                &Wt8[5 * 4096 + (w * 16 + l16) * 64 + kc * 32 + quad * 8]);
        }
        const float4 b4 = *reinterpret_cast<const float4*>(&bxt[chBase]);
        #pragma unroll
        for (int pt = 0; pt < 4; ++pt) {
            f32x4 acc = (f32x4){0.f, 0.f, 0.f, 0.f};
            #pragma unroll
            for (int kc = 0; kc < 2; ++kc) {
                bf16x8 hsf = *reinterpret_cast<const bf16x8*>(
                    &bufA[pt * 16 + l16][kc * 32 + quad * 8]);
                acc = __builtin_amdgcn_mfma_f32_16x16x32_bf16(afS[kc], hsf, acc, 0, 0, 0);
            }
            #pragma unroll
            for (int kc = 0; kc < 2; ++kc) {
                bf16x8 htf = *reinterpret_cast<const bf16x8*>(
                    &bufC[pt * 16 + l16][kc * 32 + quad * 8]);
                acc = __builtin_amdgcn_mfma_f32_16x16x32_bf16(afT[kc], htf, acc, 0, 0, 0);
            }
            const float zb[4] = {acc[0] + b4.x, acc[1] + b4.y, acc[2] + b4.z, acc[3] + b4.w};
            f32x4 h;
            #pragma unroll
            for (int r = 0; r < 4; ++r) {
                const float z = 1.0f / (1.0f + __expf(-zb[r]));
                h[r] = z * HSr[pt][r] + (1.0f - z) * HTr[pt][r];
            }
            t[pt] = h;
        }
    }
    __syncthreads();
    writeBuf(bufB, t, false);
    __syncthreads();

    gemm(bufB, 6, bh1, t);                  // H1 = relu(H@Wh1+b)
    __syncthreads();
    writeBuf(bufA, t, true);
    __syncthreads();

    gemm(bufA, 7, bh2, t);                  // out = X + H1@Wh2+b
    #pragma unroll
    for (int pt = 0; pt < 4; ++pt) {
        const long pos = p0 + pt * 16 + l16;
        const float4 xv = *reinterpret_cast<const float4*>(&X[pos * 64 + chBase]);
        float4 o;
        o.x = t[pt][0] + xv.x; o.y = t[pt][1] + xv.y;
        o.z = t[pt][2] + xv.z; o.w = t[pt][3] + xv.w;
        *reinterpret_cast<float4*>(&out[pos * 64 + chBase]) = o;
    }
}

// ---------------------------------------------------------------------------
extern "C" void kernel_launch(void* const* d_in, const int* in_sizes, int n_in,
                              void* d_out, int out_size, void* d_ws, size_t ws_size,
                              hipStream_t stream) {
    const float* X   = (const float*)d_in[0];
    const float* TLE = (const float*)d_in[1];
    const int* kpm   = (const int*)d_in[2];

    const float* sa_Wq = (const float*)d_in[3];  const float* sa_bq = (const float*)d_in[4];
    const float* sa_Wk = (const float*)d_in[5];  const float* sa_bk = (const float*)d_in[6];
    const float* sa_Wv = (const float*)d_in[7];  const float* sa_bv = (const float*)d_in[8];
    const float* sa_Wo1 = (const float*)d_in[9];  const float* sa_bo1 = (const float*)d_in[10];
    const float* sa_Wo2 = (const float*)d_in[11]; const float* sa_bo2 = (const float*)d_in[12];
    const float* ta_Wq = (const float*)d_in[13]; const float* ta_bq = (const float*)d_in[14];
    const float* ta_Wk = (const float*)d_in[15]; const float* ta_bk = (const float*)d_in[16];
    const float* ta_Wv = (const float*)d_in[17]; const float* ta_bv = (const float*)d_in[18];
    const float* ta_Wo1 = (const float*)d_in[19]; const float* ta_bo1 = (const float*)d_in[20];
    const float* ta_Wo2 = (const float*)d_in[21]; const float* ta_bo2 = (const float*)d_in[22];
    const float* g_Wxs = (const float*)d_in[23];
    const float* g_Wxt = (const float*)d_in[24]; const float* g_bxt = (const float*)d_in[25];
    const float* g_Wh1 = (const float*)d_in[26]; const float* g_bh1 = (const float*)d_in[27];
    const float* g_Wh2 = (const float*)d_in[28]; const float* g_bh2 = (const float*)d_in[29];

    unsigned short* wsp = (unsigned short*)d_ws;
    unsigned short* qt  = wsp + 0L * P64;
    unsigned short* kt  = wsp + 1L * P64;
    unsigned short* vt  = wsp + 2L * P64;
    unsigned short* HSb = wsp + 3L * P64;
    unsigned short* HTb = wsp + 4L * P64;
    unsigned short* Wt  = wsp + 5L * P64;            // 6*64*192 bf16
    unsigned short* Wt8 = Wt + 6 * 12288;            // 8*64*64 bf16

    float* out = (float*)d_out;

    hipLaunchKernelGGL(wprep_all, dim3(416), dim3(256), 0, stream,
                       sa_Wq, sa_Wk, sa_Wv, ta_Wq, ta_Wk, ta_Wv,
                       sa_Wo1, sa_Wo2, ta_Wo1, ta_Wo2, g_Wxs, g_Wxt, g_Wh1, g_Wh2,
                       Wt, Wt8);

    hipLaunchKernelGGL(fused_sattn, dim3(BB * TT), dim3(512), 0, stream,
                       X, TLE, Wt,
                       sa_bq, sa_bk, sa_bv, ta_bq, ta_bk, ta_bv,
                       qt, kt, vt, HSb);

    hipLaunchKernelGGL(tattn_kernel, dim3(BB * NN), dim3(192), 0, stream,
                       qt, kt, vt, kpm, HTb);

    hipLaunchKernelGGL(epi_kernel, dim3(PTOT / 64), dim3(256), 0, stream,
                       X, HSb, HTb, Wt8,
                       sa_bo1, sa_bo2, ta_bo1, ta_bo2, g_bxt, g_bh1, g_bh2,
                       out);
}

// Round 10
// 268.690 us; speedup vs baseline: 1.0331x; 1.0331x over previous
//
#include <hip/hip_runtime.h>
#include <math.h>

#define BB 16
#define TT 24
#define NN 128
#define DD 64
#define PTOT (BB * TT * NN)   // 49152 positions
#define P64  (PTOT * 64)      // elements per (B,T,N,64) buffer

typedef __attribute__((ext_vector_type(8))) short bf16x8;
typedef __attribute__((ext_vector_type(4))) float f32x4;

__device__ __forceinline__ unsigned short f2bf(float f) {
    unsigned u = __builtin_bit_cast(unsigned, f);
    u = (u + 0x7fffu + ((u >> 16) & 1u)) >> 16;   // round-to-nearest-even
    return (unsigned short)u;
}
__device__ __forceinline__ void unpack8(uint4 u, float* f) {
    f[0] = __builtin_bit_cast(float, u.x << 16);
    f[1] = __builtin_bit_cast(float, u.x & 0xFFFF0000u);
    f[2] = __builtin_bit_cast(float, u.y << 16);
    f[3] = __builtin_bit_cast(float, u.y & 0xFFFF0000u);
    f[4] = __builtin_bit_cast(float, u.z << 16);
    f[5] = __builtin_bit_cast(float, u.z & 0xFFFF0000u);
    f[6] = __builtin_bit_cast(float, u.w << 16);
    f[7] = __builtin_bit_cast(float, u.w & 0xFFFF0000u);
}
__device__ __forceinline__ uint4 pack8(const float* f) {
    uint4 o;
    o.x = (unsigned)f2bf(f[0]) | ((unsigned)f2bf(f[1]) << 16);
    o.y = (unsigned)f2bf(f[2]) | ((unsigned)f2bf(f[3]) << 16);
    o.z = (unsigned)f2bf(f[4]) | ((unsigned)f2bf(f[5]) << 16);
    o.w = (unsigned)f2bf(f[6]) | ((unsigned)f2bf(f[7]) << 16);
    return o;
}

// ---------------------------------------------------------------------------
// Kernel 0: combined weight prep.
// blocks 0..287: 6 proj weights (192x64) -> bf16 [j][n][k]  (Wt)
// blocks 288..415: 8 epi weights (64x64) -> bf16 [mat][n][k] (Wt8)
// ---------------------------------------------------------------------------
__global__ __launch_bounds__(256) void wprep_all(
    const float* __restrict__ W0, const float* __restrict__ W1,
    const float* __restrict__ W2, const float* __restrict__ W3,
    const float* __restrict__ W4, const float* __restrict__ W5,
    const float* __restrict__ E0, const float* __restrict__ E1,
    const float* __restrict__ E2, const float* __restrict__ E3,
    const float* __restrict__ E4, const float* __restrict__ E5,
    const float* __restrict__ E6, const float* __restrict__ E7,
    unsigned short* __restrict__ Wt, unsigned short* __restrict__ Wt8)
{
    const int bid = blockIdx.x;
    if (bid < 288) {
        const float* Ws[6] = {W0, W1, W2, W3, W4, W5};
        const int e = bid * 256 + threadIdx.x;          // < 73728
        const int j = e / 12288;
        const int r = e % 12288;
        const int k = r / 64;
        const int n = r % 64;
        Wt[j * 12288 + n * 192 + k] = f2bf(Ws[j][k * 64 + n]);
    } else {
        const float* Es[8] = {E0, E1, E2, E3, E4, E5, E6, E7};
        const int e = (bid - 288) * 256 + threadIdx.x;  // < 32768
        const int mat = e >> 12;
        const int r = e & 4095;
        const int k = r >> 6;
        const int n = r & 63;
        Wt8[mat * 4096 + n * 64 + k] = f2bf(Es[mat][k * 64 + n]);
    }
}

// ---------------------------------------------------------------------------
// Kernel 1: FUSED 6-way QKV projection + spatial attention, 512 threads.
// One block per (b,t): 128 positions, 8 waves.
// GEMM phase (BARRIER-FREE): wave w = (channel tile nt = w&3, mat group
//   mg = (w>>2)*3).  18 weight A-frags CACHED IN VGPRS (loaded once).
//   Loop over 8 pos-tiles: stream XE B-frags from global (12 float4 loads,
//   fp32->bf16), then 3 mats x 6 kc MFMAs (3 independent acc chains).
//   mg=0 (spatial q/k/v) -> swizzled bf16 LDS; mg=3 (temporal) -> global bf16.
//   Branch is wave-uniform.  Swizzle g=(nt+(quad>>1)*4+pos)&7 (2-way, free).
// Attention phase: wave = head; k/v LDS reads wave-broadcast; lane owns
//   2 query rows.  Single-pass softmax w/o max (inputs relu'd, dots bounded).
// LDS: 3*128*64*2 = 49152 B -> 2 blocks/CU (16 waves), all 384 blocks resident.
// ---------------------------------------------------------------------------
__global__ __launch_bounds__(512, 4) void fused_sattn(
    const float* __restrict__ X, const float* __restrict__ TLE,
    const unsigned short* __restrict__ Wt,   // [6][64][192] bf16
    const float* __restrict__ b0, const float* __restrict__ b1,
    const float* __restrict__ b2, const float* __restrict__ b3,
    const float* __restrict__ b4, const float* __restrict__ b5,
    unsigned short* __restrict__ qt, unsigned short* __restrict__ kt,
    unsigned short* __restrict__ vt,
    unsigned short* __restrict__ HS)
{
    __shared__ __align__(16) unsigned short qq[128 * 64];
    __shared__ __align__(16) unsigned short kk[128 * 64];
    __shared__ __align__(16) unsigned short vv[128 * 64];
    const int tid = threadIdx.x;
    const long p0 = (long)blockIdx.x * 128;
    const int w = tid >> 6, l = tid & 63, quad = l >> 4, l16 = l & 15;

    const int nt = w & 3;            // channel tile (n = nt*16 + l16)
    const int mg = (w >> 2) * 3;     // mat group start: 0 = spatial, 3 = temporal

    // ---- cache 18 weight A-fragments in VGPRs (forces register residency) ----
    bf16x8 wf[3][6];
    #pragma unroll
    for (int m3 = 0; m3 < 3; ++m3)
        #pragma unroll
        for (int kc = 0; kc < 6; ++kc)
            wf[m3][kc] = *reinterpret_cast<const bf16x8*>(
                &Wt[(mg + m3) * 12288 + (nt * 16 + l16) * 192 + kc * 32 + quad * 8]);

    const float* bias_p[6] = {b0, b1, b2, b3, b4, b5};
    float4 bias[3];
    #pragma unroll
    for (int m3 = 0; m3 < 3; ++m3)
        bias[m3] = *reinterpret_cast<const float4*>(
            &bias_p[mg + m3][nt * 16 + quad * 4]);

    unsigned short* bufS[3] = {qq, kk, vv};
    unsigned short* dstT[3] = {qt, kt, vt};
    const int sub = (quad & 1) * 4;
    const int gq  = (quad >> 1) * 4 + nt;     // + pos, &7 below

    for (int pt = 0; pt < 8; ++pt) {
        const int pos  = pt * 16 + l16;
        const long prow = p0 + pos;

        // ---- stream B fragments from global (fragment order), convert ----
        bf16x8 Bf[6];
        #pragma unroll
        for (int kc = 0; kc < 6; ++kc) {
            const int k0 = kc * 32 + quad * 8;
            const float* src = (k0 < 64) ? X + prow * 64 + k0
                                         : TLE + prow * 128 + (k0 - 64);
            const float4 a = *reinterpret_cast<const float4*>(src);
            const float4 b = *reinterpret_cast<const float4*>(src + 4);
            bf16x8 f;
            f[0] = (short)f2bf(a.x); f[1] = (short)f2bf(a.y);
            f[2] = (short)f2bf(a.z); f[3] = (short)f2bf(a.w);
            f[4] = (short)f2bf(b.x); f[5] = (short)f2bf(b.y);
            f[6] = (short)f2bf(b.z); f[7] = (short)f2bf(b.w);
            Bf[kc] = f;
        }

        // ---- 3 independent MFMA chains ----
        f32x4 acc[3];
        #pragma unroll
        for (int m3 = 0; m3 < 3; ++m3) acc[m3] = (f32x4){0.f, 0.f, 0.f, 0.f};
        #pragma unroll
        for (int kc = 0; kc < 6; ++kc)
            #pragma unroll
            for (int m3 = 0; m3 < 3; ++m3)
                acc[m3] = __builtin_amdgcn_mfma_f32_16x16x32_bf16(
                    wf[m3][kc], Bf[kc], acc[m3], 0, 0, 0);

        #pragma unroll
        for (int m3 = 0; m3 < 3; ++m3) {
            ushort4 pk;
            pk.x = f2bf(fmaxf(acc[m3][0] + bias[m3].x, 0.f));
            pk.y = f2bf(fmaxf(acc[m3][1] + bias[m3].y, 0.f));
            pk.z = f2bf(fmaxf(acc[m3][2] + bias[m3].z, 0.f));
            pk.w = f2bf(fmaxf(acc[m3][3] + bias[m3].w, 0.f));
            if (mg == 0) {                       // wave-uniform branch
                const int g = (gq + pos) & 7;
                *reinterpret_cast<ushort4*>(
                    &bufS[m3][pos * 64 + g * 8 + sub]) = pk;
            } else {
                *reinterpret_cast<ushort4*>(
                    &dstT[m3][prow * 64 + nt * 16 + quad * 4]) = pk;
            }
        }
    }
    __syncthreads();

    // ---------------- attention phase: wave = head ----------------
    const int h  = w;
    const int ph = (h >> 1) | ((h & 1) << 2);     // storage perm of chunk id
    const float scale = 0.35355339059327373f;     // 1/sqrt(8)

    float q[2][8];
    #pragma unroll
    for (int r2 = 0; r2 < 2; ++r2) {
        const int row = l + r2 * 64;
        const uint4 qu = *reinterpret_cast<const uint4*>(
            &qq[row * 64 + (((ph + row) & 7) << 3)]);
        float qf[8]; unpack8(qu, qf);
        #pragma unroll
        for (int d = 0; d < 8; ++d) q[r2][d] = qf[d] * scale;
    }

    float sum[2] = {0.f, 0.f};
    float acc[2][8];
    #pragma unroll
    for (int r2 = 0; r2 < 2; ++r2)
        #pragma unroll
        for (int d = 0; d < 8; ++d) acc[r2][d] = 0.f;

    for (int m = 0; m < NN; ++m) {
        const int co = ((ph + m) & 7) << 3;       // wave-uniform -> broadcast
        const uint4 ku = *reinterpret_cast<const uint4*>(&kk[m * 64 + co]);
        const uint4 vu = *reinterpret_cast<const uint4*>(&vv[m * 64 + co]);
        float kf[8], vf[8];
        unpack8(ku, kf); unpack8(vu, vf);
        #pragma unroll
        for (int r2 = 0; r2 < 2; ++r2) {
            float s = q[r2][0] * kf[0];
            #pragma unroll
            for (int d = 1; d < 8; ++d) s = fmaf(q[r2][d], kf[d], s);
            const float e = __expf(s);
            sum[r2] += e;
            #pragma unroll
            for (int d = 0; d < 8; ++d) acc[r2][d] = fmaf(e, vf[d], acc[r2][d]);
        }
    }

    #pragma unroll
    for (int r2 = 0; r2 < 2; ++r2) {
        const int row = l + r2 * 64;
        const float inv = 1.0f / sum[r2];
        float o[8];
        #pragma unroll
        for (int d = 0; d < 8; ++d) o[d] = acc[r2][d] * inv;
        *reinterpret_cast<uint4*>(&HS[(p0 + row) * 64 + h * 8]) = pack8(o);
    }
}

// ---------------------------------------------------------------------------
// Kernel 2: temporal attention (causal + key padding), bf16 I/O.
// One block per (b, n); 192 threads = (head h, query time i).
// ---------------------------------------------------------------------------
__global__ __launch_bounds__(192) void tattn_kernel(
    const unsigned short* __restrict__ Q, const unsigned short* __restrict__ Kb,
    const unsigned short* __restrict__ V, const int* __restrict__ kpm,
    unsigned short* __restrict__ O)
{
    __shared__ float kk[8][TT][8];
    __shared__ float vv[8][TT][8];
    const int tid = threadIdx.x;
    const int n = blockIdx.x & (NN - 1);
    const int b = blockIdx.x >> 7;

    {   // staging: thread = (head hs, time j)
        const int hs = tid / TT;
        const int j  = tid % TT;
        const long g = (((long)(b * TT + j)) * NN + n) * 64 + hs * 8;
        uint4 ku = *reinterpret_cast<const uint4*>(&Kb[g]);
        uint4 vu = *reinterpret_cast<const uint4*>(&V[g]);
        float kf[8], vf[8];
        unpack8(ku, kf); unpack8(vu, vf);
        #pragma unroll
        for (int d = 0; d < 8; ++d) { kk[hs][j][d] = kf[d]; vv[hs][j][d] = vf[d]; }
    }

    const int h = tid / TT;
    const int i = tid % TT;
    const long qb = (((long)(b * TT + i)) * NN + n) * 64 + h * 8;
    float q[8];
    {
        uint4 qu = *reinterpret_cast<const uint4*>(&Q[qb]);
        unpack8(qu, q);
    }
    __syncthreads();

    const int kp = kpm[b];
    const float scale = 0.35355339059327373f;

    float s[TT];
    #pragma unroll
    for (int j = 0; j < TT; ++j) {
        float t = 0.0f;
        #pragma unroll
        for (int d = 0; d < 8; ++d) t = fmaf(q[d], kk[h][j][d], t);
        s[j] = (j <= i && j < kp) ? t * scale : -INFINITY;
    }
    float mx = -INFINITY;
    #pragma unroll
    for (int j = 0; j < TT; ++j) mx = fmaxf(mx, s[j]);

    float sum = 0.0f;
    float acc[8];
    #pragma unroll
    for (int d = 0; d < 8; ++d) acc[d] = 0.0f;
    #pragma unroll
    for (int j = 0; j < TT; ++j) {
        const float e = __expf(s[j] - mx);  // masked -> exp(-inf)=0
        sum += e;
        #pragma unroll
        for (int d = 0; d < 8; ++d) acc[d] = fmaf(e, vv[h][j][d], acc[d]);
    }
    const float inv = 1.0f / sum;
    float o[8];
    #pragma unroll
    for (int d = 0; d < 8; ++d) o[d] = acc[d] * inv;
    *reinterpret_cast<uint4*>(&O[qb]) = pack8(o);
}

// ---------------------------------------------------------------------------
// Kernel 3: epilogue via bf16 MFMA, swapped operands.
// Block = 256 thr (4 waves), 64-position tile.  Grid = PTOT/64 = 768.
// ---------------------------------------------------------------------------
__global__ __launch_bounds__(256) void epi_kernel(
    const float* __restrict__ X,
    const unsigned short* __restrict__ HSb, const unsigned short* __restrict__ HTb,
    const unsigned short* __restrict__ Wt8,  // [8][64][64] bf16
    const float* __restrict__ sbo1, const float* __restrict__ sbo2,
    const float* __restrict__ tbo1, const float* __restrict__ tbo2,
    const float* __restrict__ bxt,
    const float* __restrict__ bh1, const float* __restrict__ bh2,
    float* __restrict__ out)
{
    constexpr int RS = 72;
    __shared__ __align__(16) unsigned short bufA[64][RS], bufB[64][RS], bufC[64][RS];
    const int tid = threadIdx.x;
    const long p0 = (long)blockIdx.x * 64;
    const int w = tid >> 6, l = tid & 63, quad = l >> 4, l16 = l & 15;
    const int chBase = w * 16 + quad * 4;

    #pragma unroll
    for (int i = 0; i < 4; ++i) {
        const int idx = tid + i * 256;      // < 1024
        const int m = idx >> 4;
        const int c = (idx & 15) * 4;
        *reinterpret_cast<ushort4*>(&bufA[m][c]) =
            *reinterpret_cast<const ushort4*>(&HSb[(p0 + m) * 64 + c]);
        *reinterpret_cast<ushort4*>(&bufC[m][c]) =
            *reinterpret_cast<const ushort4*>(&HTb[(p0 + m) * 64 + c]);
    }
    __syncthreads();

    auto gemm = [&](const unsigned short (*in)[RS], int mat,
                    const float* __restrict__ bias, f32x4* accO) {
        bf16x8 af[2];
        #pragma unroll
        for (int kc = 0; kc < 2; ++kc)
            af[kc] = *reinterpret_cast<const bf16x8*>(
                &Wt8[mat * 4096 + (w * 16 + l16) * 64 + kc * 32 + quad * 8]);
        const float4 b4 = *reinterpret_cast<const float4*>(&bias[chBase]);
        #pragma unroll
        for (int pt = 0; pt < 4; ++pt) {
            f32x4 acc = (f32x4){0.f, 0.f, 0.f, 0.f};
            #pragma unroll
            for (int kc = 0; kc < 2; ++kc) {
                bf16x8 bf = *reinterpret_cast<const bf16x8*>(
                    &in[pt * 16 + l16][kc * 32 + quad * 8]);
                acc = __builtin_amdgcn_mfma_f32_16x16x32_bf16(af[kc], bf, acc, 0, 0, 0);
            }
            acc[0] += b4.x; acc[1] += b4.y; acc[2] += b4.z; acc[3] += b4.w;
            accO[pt] = acc;
        }
    };

    auto writeBuf = [&](unsigned short (*dst)[RS], const f32x4* v, bool relu) {
        #pragma unroll
        for (int pt = 0; pt < 4; ++pt) {
            float a0 = v[pt][0], a1 = v[pt][1], a2 = v[pt][2], a3 = v[pt][3];
            if (relu) { a0 = fmaxf(a0, 0.f); a1 = fmaxf(a1, 0.f);
                        a2 = fmaxf(a2, 0.f); a3 = fmaxf(a3, 0.f); }
            ushort4 pk; pk.x = f2bf(a0); pk.y = f2bf(a1); pk.z = f2bf(a2); pk.w = f2bf(a3);
            *reinterpret_cast<ushort4*>(&dst[pt * 16 + l16][chBase]) = pk;
        }
    };

    f32x4 t[4], HSr[4], HTr[4];

    gemm(bufA, 0, sbo1, t);                 // HS1 = relu(HS@sWo1+b)
    __syncthreads();
    writeBuf(bufB, t, true);
    __syncthreads();

    gemm(bufB, 1, sbo2, HSr);               // HS2 (fp32 regs)
    __syncthreads();
    writeBuf(bufA, HSr, false);
    __syncthreads();

    gemm(bufC, 2, tbo1, t);                 // HT1 = relu(HT@tWo1+b)
    __syncthreads();
    writeBuf(bufB, t, true);
    __syncthreads();

    gemm(bufB, 3, tbo2, HTr);               // HT2 (fp32 regs)
    __syncthreads();
    writeBuf(bufC, HTr, false);
    __syncthreads();

    // ---- gate ----
    {
        bf16x8 afS[2], afT[2];
        #pragma unroll
        for (int kc = 0; kc < 2; ++kc) {
            afS[kc] = *reinterpret_cast<const bf16x8*>(
                &Wt8[4 * 4096 + (w * 16 + l16) * 64 + kc * 32 + quad * 8]);
            afT[kc] = *reinterpret_cast<const bf16x8*>(
                &Wt8[5 * 4096 + (w * 16 + l16) * 64 + kc * 32 + quad * 8]);
        }
        const float4 b4 = *reinterpret_cast<const float4*>(&bxt[chBase]);
        #pragma unroll
        for (int pt = 0; pt < 4; ++pt) {
            f32x4 acc = (f32x4){0.f, 0.f, 0.f, 0.f};
            #pragma unroll
            for (int kc = 0; kc < 2; ++kc) {
                bf16x8 hsf = *reinterpret_cast<const bf16x8*>(
                    &bufA[pt * 16 + l16][kc * 32 + quad * 8]);
                acc = __builtin_amdgcn_mfma_f32_16x16x32_bf16(afS[kc], hsf, acc, 0, 0, 0);
            }
            #pragma unroll
            for (int kc = 0; kc < 2; ++kc) {
                bf16x8 htf = *reinterpret_cast<const bf16x8*>(
                    &bufC[pt * 16 + l16][kc * 32 + quad * 8]);
                acc = __builtin_amdgcn_mfma_f32_16x16x32_bf16(afT[kc], htf, acc, 0, 0, 0);
            }
            const float zb[4] = {acc[0] + b4.x, acc[1] + b4.y, acc[2] + b4.z, acc[3] + b4.w};
            f32x4 h;
            #pragma unroll
            for (int r = 0; r < 4; ++r) {
                const float z = 1.0f / (1.0f + __expf(-zb[r]));
                h[r] = z * HSr[pt][r] + (1.0f - z) * HTr[pt][r];
            }
            t[pt] = h;
        }
    }
    __syncthreads();
    writeBuf(bufB, t, false);
    __syncthreads();

    gemm(bufB, 6, bh1, t);                  // H1 = relu(H@Wh1+b)
    __syncthreads();
    writeBuf(bufA, t, true);
    __syncthreads();

    gemm(bufA, 7, bh2, t);                  // out = X + H1@Wh2+b
    #pragma unroll
    for (int pt = 0; pt < 4; ++pt) {
        const long pos = p0 + pt * 16 + l16;
        const float4 xv = *reinterpret_cast<const float4*>(&X[pos * 64 + chBase]);
        float4 o;
        o.x = t[pt][0] + xv.x; o.y = t[pt][1] + xv.y;
        o.z = t[pt][2] + xv.z; o.w = t[pt][3] + xv.w;
        *reinterpret_cast<float4*>(&out[pos * 64 + chBase]) = o;
    }
}

// ---------------------------------------------------------------------------
extern "C" void kernel_launch(void* const* d_in, const int* in_sizes, int n_in,
                              void* d_out, int out_size, void* d_ws, size_t ws_size,
                              hipStream_t stream) {
    const float* X   = (const float*)d_in[0];
    const float* TLE = (const float*)d_in[1];
    const int* kpm   = (const int*)d_in[2];

    const float* sa_Wq = (const float*)d_in[3];  const float* sa_bq = (const float*)d_in[4];
    const float* sa_Wk = (const float*)d_in[5];  const float* sa_bk = (const float*)d_in[6];
    const float* sa_Wv = (const float*)d_in[7];  const float* sa_bv = (const float*)d_in[8];
    const float* sa_Wo1 = (const float*)d_in[9];  const float* sa_bo1 = (const float*)d_in[10];
    const float* sa_Wo2 = (const float*)d_in[11]; const float* sa_bo2 = (const float*)d_in[12];
    const float* ta_Wq = (const float*)d_in[13]; const float* ta_bq = (const float*)d_in[14];
    const float* ta_Wk = (const float*)d_in[15]; const float* ta_bk = (const float*)d_in[16];
    const float* ta_Wv = (const float*)d_in[17]; const float* ta_bv = (const float*)d_in[18];
    const float* ta_Wo1 = (const float*)d_in[19]; const float* ta_bo1 = (const float*)d_in[20];
    const float* ta_Wo2 = (const float*)d_in[21]; const float* ta_bo2 = (const float*)d_in[22];
    const float* g_Wxs = (const float*)d_in[23];
    const float* g_Wxt = (const float*)d_in[24]; const float* g_bxt = (const float*)d_in[25];
    const float* g_Wh1 = (const float*)d_in[26]; const float* g_bh1 = (const float*)d_in[27];
    const float* g_Wh2 = (const float*)d_in[28]; const float* g_bh2 = (const float*)d_in[29];

    unsigned short* wsp = (unsigned short*)d_ws;
    unsigned short* qt  = wsp + 0L * P64;
    unsigned short* kt  = wsp + 1L * P64;
    unsigned short* vt  = wsp + 2L * P64;
    unsigned short* HSb = wsp + 3L * P64;
    unsigned short* HTb = wsp + 4L * P64;
    unsigned short* Wt  = wsp + 5L * P64;            // 6*64*192 bf16
    unsigned short* Wt8 = Wt + 6 * 12288;            // 8*64*64 bf16

    float* out = (float*)d_out;

    hipLaunchKernelGGL(wprep_all, dim3(416), dim3(256), 0, stream,
                       sa_Wq, sa_Wk, sa_Wv, ta_Wq, ta_Wk, ta_Wv,
                       sa_Wo1, sa_Wo2, ta_Wo1, ta_Wo2, g_Wxs, g_Wxt, g_Wh1, g_Wh2,
                       Wt, Wt8);

    hipLaunchKernelGGL(fused_sattn, dim3(BB * TT), dim3(512), 0, stream,
                       X, TLE, Wt,
                       sa_bq, sa_bk, sa_bv, ta_bq, ta_bk, ta_bv,
                       qt, kt, vt, HSb);

    hipLaunchKernelGGL(tattn_kernel, dim3(BB * NN), dim3(192), 0, stream,
                       qt, kt, vt, kpm, HTb);

    hipLaunchKernelGGL(epi_kernel, dim3(PTOT / 64), dim3(256), 0, stream,
                       X, HSb, HTb, Wt8,
                       sa_bo1, sa_bo2, ta_bo1, ta_bo2, g_bxt, g_bh1, g_bh2,
                       out);
}

// Round 11
// 240.978 us; speedup vs baseline: 1.1519x; 1.1150x over previous
//
#include <hip/hip_runtime.h>
#include <math.h>

#define BB 16
#define TT 24
#define NN 128
#define DD 64
#define PTOT (BB * TT * NN)   // 49152 positions
#define P64  (PTOT * 64)      // elements per (B,T,N,64) buffer

typedef __attribute__((ext_vector_type(8))) short bf16x8;
typedef __attribute__((ext_vector_type(4))) float f32x4;

__device__ __forceinline__ unsigned short f2bf(float f) {
    unsigned u = __builtin_bit_cast(unsigned, f);
    u = (u + 0x7fffu + ((u >> 16) & 1u)) >> 16;   // round-to-nearest-even
    return (unsigned short)u;
}
__device__ __forceinline__ void unpack8(uint4 u, float* f) {
    f[0] = __builtin_bit_cast(float, u.x << 16);
    f[1] = __builtin_bit_cast(float, u.x & 0xFFFF0000u);
    f[2] = __builtin_bit_cast(float, u.y << 16);
    f[3] = __builtin_bit_cast(float, u.y & 0xFFFF0000u);
    f[4] = __builtin_bit_cast(float, u.z << 16);
    f[5] = __builtin_bit_cast(float, u.z & 0xFFFF0000u);
    f[6] = __builtin_bit_cast(float, u.w << 16);
    f[7] = __builtin_bit_cast(float, u.w & 0xFFFF0000u);
}
__device__ __forceinline__ uint4 pack8(const float* f) {
    uint4 o;
    o.x = (unsigned)f2bf(f[0]) | ((unsigned)f2bf(f[1]) << 16);
    o.y = (unsigned)f2bf(f[2]) | ((unsigned)f2bf(f[3]) << 16);
    o.z = (unsigned)f2bf(f[4]) | ((unsigned)f2bf(f[5]) << 16);
    o.w = (unsigned)f2bf(f[6]) | ((unsigned)f2bf(f[7]) << 16);
    return o;
}

// ---------------------------------------------------------------------------
// Kernel 0: combined weight prep.
// blocks 0..287: 6 proj weights (192x64) -> bf16 [j][n][k]  (Wt)
// blocks 288..415: 8 epi weights (64x64) -> bf16 [mat][n][k] (Wt8)
// ---------------------------------------------------------------------------
__global__ __launch_bounds__(256) void wprep_all(
    const float* __restrict__ W0, const float* __restrict__ W1,
    const float* __restrict__ W2, const float* __restrict__ W3,
    const float* __restrict__ W4, const float* __restrict__ W5,
    const float* __restrict__ E0, const float* __restrict__ E1,
    const float* __restrict__ E2, const float* __restrict__ E3,
    const float* __restrict__ E4, const float* __restrict__ E5,
    const float* __restrict__ E6, const float* __restrict__ E7,
    unsigned short* __restrict__ Wt, unsigned short* __restrict__ Wt8)
{
    const int bid = blockIdx.x;
    if (bid < 288) {
        const float* Ws[6] = {W0, W1, W2, W3, W4, W5};
        const int e = bid * 256 + threadIdx.x;          // < 73728
        const int j = e / 12288;
        const int r = e % 12288;
        const int k = r / 64;
        const int n = r % 64;
        Wt[j * 12288 + n * 192 + k] = f2bf(Ws[j][k * 64 + n]);
    } else {
        const float* Es[8] = {E0, E1, E2, E3, E4, E5, E6, E7};
        const int e = (bid - 288) * 256 + threadIdx.x;  // < 32768
        const int mat = e >> 12;
        const int r = e & 4095;
        const int k = r >> 6;
        const int n = r & 63;
        Wt8[mat * 4096 + n * 64 + k] = f2bf(Es[mat][k * 64 + n]);
    }
}

// ---------------------------------------------------------------------------
// Kernel 1: fused 6-way QKV projection via bf16 MFMA (R7's proven structure).
// Block = 256 thr (4 waves), 64-position tile.  Grid = PTOT/64 = 768.
// XE^T frags cached in VGPRs (24), weights streamed once per (j,nt) tile.
// bf16 outputs in attention-friendly layouts:
//   spatial  (j<3): [bt][head][n][8]  (head-major -> sattn stages contiguously)
//   temporal (j>=3): [b][n][t][64]    (-> tattn stages contiguously)
// ---------------------------------------------------------------------------
__global__ __launch_bounds__(256) void proj_kernel(
    const float* __restrict__ X, const float* __restrict__ TLE,
    const unsigned short* __restrict__ Wt,   // [6][64][192] bf16
    const float* __restrict__ b0, const float* __restrict__ b1,
    const float* __restrict__ b2, const float* __restrict__ b3,
    const float* __restrict__ b4, const float* __restrict__ b5,
    unsigned short* __restrict__ qs, unsigned short* __restrict__ ks,
    unsigned short* __restrict__ vs,
    unsigned short* __restrict__ qt, unsigned short* __restrict__ kt,
    unsigned short* __restrict__ vt)
{
    __shared__ __align__(16) unsigned short xe[64][200];  // [m][k] bf16
    const int tid = threadIdx.x;
    const long p0 = (long)blockIdx.x * 64;

    #pragma unroll
    for (int i = 0; i < 12; ++i) {                 // 64*48 float4s / 256 thr
        const int idx4 = tid + i * 256;
        const int m  = idx4 / 48;
        const int kq = idx4 % 48;
        const int k  = kq * 4;
        float4 v;
        if (k < 64) v = *reinterpret_cast<const float4*>(X + (p0 + m) * 64 + k);
        else        v = *reinterpret_cast<const float4*>(TLE + (p0 + m) * 128 + (k - 64));
        ushort4 pk;
        pk.x = f2bf(v.x); pk.y = f2bf(v.y); pk.z = f2bf(v.z); pk.w = f2bf(v.w);
        *reinterpret_cast<ushort4*>(&xe[m][k]) = pk;
    }
    __syncthreads();

    const int w    = tid >> 6;
    const int l    = tid & 63;
    const int quad = l >> 4;
    const int l16  = l & 15;

    bf16x8 xef[4][6];
    #pragma unroll
    for (int mt = 0; mt < 4; ++mt)
        #pragma unroll
        for (int kc = 0; kc < 6; ++kc)
            xef[mt][kc] = *reinterpret_cast<const bf16x8*>(
                &xe[mt * 16 + l16][kc * 32 + quad * 8]);

    const float* bs[6] = {b0, b1, b2, b3, b4, b5};
    unsigned short* Os[6] = {qs, ks, vs, qt, kt, vt};

    const int bt = blockIdx.x >> 1;          // (b,t) index
    const int b  = bt / TT;
    const int t  = bt % TT;
    const int nh = (blockIdx.x & 1) * 64;    // n offset within (b,t)

    #pragma unroll
    for (int q6 = 0; q6 < 6; ++q6) {
        const int tile = w * 6 + q6;
        const int j  = tile >> 2;            // matrix 0..5 (wave-uniform)
        const int nt = tile & 3;             // channel tile
        const unsigned short* __restrict__ Wj = Wt + j * 12288;

        bf16x8 wf[6];
        #pragma unroll
        for (int kc = 0; kc < 6; ++kc)
            wf[kc] = *reinterpret_cast<const bf16x8*>(
                &Wj[(nt * 16 + l16) * 192 + kc * 32 + quad * 8]);

        f32x4 acc[4];
        #pragma unroll
        for (int mt = 0; mt < 4; ++mt) acc[mt] = (f32x4){0.f, 0.f, 0.f, 0.f};

        #pragma unroll
        for (int kc = 0; kc < 6; ++kc)
            #pragma unroll
            for (int mt = 0; mt < 4; ++mt)
                acc[mt] = __builtin_amdgcn_mfma_f32_16x16x32_bf16(
                    wf[kc], xef[mt][kc], acc[mt], 0, 0, 0);

        const int ch0 = nt * 16 + quad * 4;  // 4 consecutive channels
        const float4 b4 = *reinterpret_cast<const float4*>(&bs[j][ch0]);
        unsigned short* __restrict__ Oj = Os[j];

        #pragma unroll
        for (int mt = 0; mt < 4; ++mt) {
            const int pos = mt * 16 + l16;
            const int n = nh + pos;
            ushort4 pk;
            pk.x = f2bf(fmaxf(acc[mt][0] + b4.x, 0.0f));
            pk.y = f2bf(fmaxf(acc[mt][1] + b4.y, 0.0f));
            pk.z = f2bf(fmaxf(acc[mt][2] + b4.z, 0.0f));
            pk.w = f2bf(fmaxf(acc[mt][3] + b4.w, 0.0f));
            if (j < 3) {
                // spatial: [bt][h][n][8]
                *reinterpret_cast<ushort4*>(
                    &Oj[(long)bt * 8192 + (ch0 >> 3) * 1024 + n * 8 + (ch0 & 7)]) = pk;
            } else {
                // temporal: [b][n][t][64]
                *reinterpret_cast<ushort4*>(
                    &Oj[(((long)(b * NN + n)) * TT + t) * 64 + ch0]) = pk;
            }
        }
    }
}

// ---------------------------------------------------------------------------
// Kernel 2: spatial attention.  One block per (bt, head): 3072 blocks, 128 thr.
// Head-major input [bt][h][n][8] -> staging is one contiguous 2 KB chunk per
// matrix; k/v unpacked to fp32 LDS (scale folded into k).  Thread = query row.
// Single-pass softmax w/o max (inputs relu'd, dots bounded << exp overflow).
// LDS 8 KB -> high TLP (10+ blocks/CU).
// ---------------------------------------------------------------------------
__global__ __launch_bounds__(128) void sattn_kernel(
    const unsigned short* __restrict__ qs, const unsigned short* __restrict__ ks,
    const unsigned short* __restrict__ vs, unsigned short* __restrict__ HS)
{
    __shared__ __align__(16) float kf[NN][8];   // 4 KB (pre-scaled)
    __shared__ __align__(16) float vf[NN][8];   // 4 KB
    const int tid = threadIdx.x;                // query row n
    const int h   = blockIdx.x & 7;
    const int bt  = blockIdx.x >> 3;
    const long base = (long)bt * 8192 + h * 1024;
    const float scale = 0.35355339059327373f;   // 1/sqrt(8)

    {   // stage: contiguous 16B per thread
        const uint4 ku = *reinterpret_cast<const uint4*>(&ks[base + tid * 8]);
        const uint4 vu = *reinterpret_cast<const uint4*>(&vs[base + tid * 8]);
        float kk[8], vv[8];
        unpack8(ku, kk); unpack8(vu, vv);
        #pragma unroll
        for (int d = 0; d < 8; ++d) { kf[tid][d] = kk[d] * scale; vf[tid][d] = vv[d]; }
    }

    float q[8];
    {
        const uint4 qu = *reinterpret_cast<const uint4*>(&qs[base + tid * 8]);
        unpack8(qu, q);
    }
    __syncthreads();

    float sum = 0.f;
    float acc[8];
    #pragma unroll
    for (int d = 0; d < 8; ++d) acc[d] = 0.f;

    for (int m = 0; m < NN; ++m) {
        const float4 ka = *reinterpret_cast<const float4*>(&kf[m][0]);
        const float4 kb = *reinterpret_cast<const float4*>(&kf[m][4]);
        const float4 va = *reinterpret_cast<const float4*>(&vf[m][0]);
        const float4 vb = *reinterpret_cast<const float4*>(&vf[m][4]);
        float s = q[0] * ka.x;
        s = fmaf(q[1], ka.y, s); s = fmaf(q[2], ka.z, s); s = fmaf(q[3], ka.w, s);
        s = fmaf(q[4], kb.x, s); s = fmaf(q[5], kb.y, s);
        s = fmaf(q[6], kb.z, s); s = fmaf(q[7], kb.w, s);
        const float e = __expf(s);
        sum += e;
        acc[0] = fmaf(e, va.x, acc[0]); acc[1] = fmaf(e, va.y, acc[1]);
        acc[2] = fmaf(e, va.z, acc[2]); acc[3] = fmaf(e, va.w, acc[3]);
        acc[4] = fmaf(e, vb.x, acc[4]); acc[5] = fmaf(e, vb.y, acc[5]);
        acc[6] = fmaf(e, vb.z, acc[6]); acc[7] = fmaf(e, vb.w, acc[7]);
    }

    const float inv = 1.0f / sum;
    float o[8];
    #pragma unroll
    for (int d = 0; d < 8; ++d) o[d] = acc[d] * inv;
    // HS layout: [pos][ch] for epi
    *reinterpret_cast<uint4*>(&HS[((long)bt * NN + tid) * 64 + h * 8]) = pack8(o);
}

// ---------------------------------------------------------------------------
// Kernel 3: temporal attention (causal + key padding), bf16 I/O.
// One block per (b, n); 192 threads = (head h, query time i).
// Input layout [b][n][t][64] -> the block's K/V region is one contiguous
// 3 KB span; staging is perfectly coalesced (192 x 16 B).
// Output HT in [b][t][n][64] (= [pos][ch]) for epi.
// ---------------------------------------------------------------------------
__global__ __launch_bounds__(192) void tattn_kernel(
    const unsigned short* __restrict__ Q, const unsigned short* __restrict__ Kb,
    const unsigned short* __restrict__ V, const int* __restrict__ kpm,
    unsigned short* __restrict__ O)
{
    __shared__ float kk[TT][64];   // 6 KB
    __shared__ float vv[TT][64];   // 6 KB
    const int tid = threadIdx.x;
    const int n = blockIdx.x & (NN - 1);
    const int b = blockIdx.x >> 7;
    const long base = ((long)(b * NN + n)) * TT * 64;   // shorts

    {   // stage: contiguous, thread f covers [t=f/8][ch=(f%8)*8 .. +7]
        const uint4 ku = *reinterpret_cast<const uint4*>(&Kb[base + tid * 8]);
        const uint4 vu = *reinterpret_cast<const uint4*>(&V[base + tid * 8]);
        float kf[8], vf[8];
        unpack8(ku, kf); unpack8(vu, vf);
        const int t0 = tid >> 3;
        const int c0 = (tid & 7) * 8;
        #pragma unroll
        for (int d = 0; d < 8; ++d) { kk[t0][c0 + d] = kf[d]; vv[t0][c0 + d] = vf[d]; }
    }

    const int h = tid / TT;
    const int i = tid % TT;
    float q[8];
    {
        const uint4 qu = *reinterpret_cast<const uint4*>(&Q[base + i * 64 + h * 8]);
        unpack8(qu, q);
    }
    __syncthreads();

    const int kp = kpm[b];
    const float scale = 0.35355339059327373f;

    float s[TT];
    #pragma unroll
    for (int j = 0; j < TT; ++j) {
        float t = 0.0f;
        #pragma unroll
        for (int d = 0; d < 8; ++d) t = fmaf(q[d], kk[j][h * 8 + d], t);
        s[j] = (j <= i && j < kp) ? t * scale : -INFINITY;
    }
    float mx = -INFINITY;
    #pragma unroll
    for (int j = 0; j < TT; ++j) mx = fmaxf(mx, s[j]);

    float sum = 0.0f;
    float acc[8];
    #pragma unroll
    for (int d = 0; d < 8; ++d) acc[d] = 0.0f;
    #pragma unroll
    for (int j = 0; j < TT; ++j) {
        const float e = __expf(s[j] - mx);  // masked -> exp(-inf)=0
        sum += e;
        #pragma unroll
        for (int d = 0; d < 8; ++d) acc[d] = fmaf(e, vv[j][h * 8 + d], acc[d]);
    }
    const float inv = 1.0f / sum;
    float o[8];
    #pragma unroll
    for (int d = 0; d < 8; ++d) o[d] = acc[d] * inv;
    // HT layout: [b][t][n][64] = [pos][ch]
    *reinterpret_cast<uint4*>(
        &O[(((long)(b * TT + i)) * NN + n) * 64 + h * 8]) = pack8(o);
}

// ---------------------------------------------------------------------------
// Kernel 4: epilogue via bf16 MFMA, swapped operands.
// Block = 256 thr (4 waves), 64-position tile.  Grid = PTOT/64 = 768.
// ---------------------------------------------------------------------------
__global__ __launch_bounds__(256) void epi_kernel(
    const float* __restrict__ X,
    const unsigned short* __restrict__ HSb, const unsigned short* __restrict__ HTb,
    const unsigned short* __restrict__ Wt8,  // [8][64][64] bf16
    const float* __restrict__ sbo1, const float* __restrict__ sbo2,
    const float* __restrict__ tbo1, const float* __restrict__ tbo2,
    const float* __restrict__ bxt,
    const float* __restrict__ bh1, const float* __restrict__ bh2,
    float* __restrict__ out)
{
    constexpr int RS = 72;
    __shared__ __align__(16) unsigned short bufA[64][RS], bufB[64][RS], bufC[64][RS];
    const int tid = threadIdx.x;
    const long p0 = (long)blockIdx.x * 64;
    const int w = tid >> 6, l = tid & 63, quad = l >> 4, l16 = l & 15;
    const int chBase = w * 16 + quad * 4;

    #pragma unroll
    for (int i = 0; i < 4; ++i) {
        const int idx = tid + i * 256;      // < 1024
        const int m = idx >> 4;
        const int c = (idx & 15) * 4;
        *reinterpret_cast<ushort4*>(&bufA[m][c]) =
            *reinterpret_cast<const ushort4*>(&HSb[(p0 + m) * 64 + c]);
        *reinterpret_cast<ushort4*>(&bufC[m][c]) =
            *reinterpret_cast<const ushort4*>(&HTb[(p0 + m) * 64 + c]);
    }
    __syncthreads();

    auto gemm = [&](const unsigned short (*in)[RS], int mat,
                    const float* __restrict__ bias, f32x4* accO) {
        bf16x8 af[2];
        #pragma unroll
        for (int kc = 0; kc < 2; ++kc)
            af[kc] = *reinterpret_cast<const bf16x8*>(
                &Wt8[mat * 4096 + (w * 16 + l16) * 64 + kc * 32 + quad * 8]);
        const float4 b4 = *reinterpret_cast<const float4*>(&bias[chBase]);
        #pragma unroll
        for (int pt = 0; pt < 4; ++pt) {
            f32x4 acc = (f32x4){0.f, 0.f, 0.f, 0.f};
            #pragma unroll
            for (int kc = 0; kc < 2; ++kc) {
                bf16x8 bf = *reinterpret_cast<const bf16x8*>(
                    &in[pt * 16 + l16][kc * 32 + quad * 8]);
                acc = __builtin_amdgcn_mfma_f32_16x16x32_bf16(af[kc], bf, acc, 0, 0, 0);
            }
            acc[0] += b4.x; acc[1] += b4.y; acc[2] += b4.z; acc[3] += b4.w;
            accO[pt] = acc;
        }
    };

    auto writeBuf = [&](unsigned short (*dst)[RS], const f32x4* v, bool relu) {
        #pragma unroll
        for (int pt = 0; pt < 4; ++pt) {
            float a0 = v[pt][0], a1 = v[pt][1], a2 = v[pt][2], a3 = v[pt][3];
            if (relu) { a0 = fmaxf(a0, 0.f); a1 = fmaxf(a1, 0.f);
                        a2 = fmaxf(a2, 0.f); a3 = fmaxf(a3, 0.f); }
            ushort4 pk; pk.x = f2bf(a0); pk.y = f2bf(a1); pk.z = f2bf(a2); pk.w = f2bf(a3);
            *reinterpret_cast<ushort4*>(&dst[pt * 16 + l16][chBase]) = pk;
        }
    };

    f32x4 t[4], HSr[4], HTr[4];

    gemm(bufA, 0, sbo1, t);                 // HS1 = relu(HS@sWo1+b)
    __syncthreads();
    writeBuf(bufB, t, true);
    __syncthreads();

    gemm(bufB, 1, sbo2, HSr);               // HS2 (fp32 regs)
    __syncthreads();
    writeBuf(bufA, HSr, false);
    __syncthreads();

    gemm(bufC, 2, tbo1, t);                 // HT1 = relu(HT@tWo1+b)
    __syncthreads();
    writeBuf(bufB, t, true);
    __syncthreads();

    gemm(bufB, 3, tbo2, HTr);               // HT2 (fp32 regs)
    __syncthreads();
    writeBuf(bufC, HTr, false);
    __syncthreads();

    // ---- gate ----
    {
        bf16x8 afS[2], afT[2];
        #pragma unroll
        for (int kc = 0; kc < 2; ++kc) {
            afS[kc] = *reinterpret_cast<const bf16x8*>(
                &Wt8[4 * 4096 + (w * 16 + l16) * 64 + kc * 32 + quad * 8]);
            afT[kc] = *reinterpret_cast<const bf16x8*>(
                &Wt8[5 * 4096 + (w * 16 + l16) * 64 + kc * 32 + quad * 8]);
        }
        const float4 b4 = *reinterpret_cast<const float4*>(&bxt[chBase]);
        #pragma unroll
        for (int pt = 0; pt < 4; ++pt) {
            f32x4 acc = (f32x4){0.f, 0.f, 0.f, 0.f};
            #pragma unroll
            for (int kc = 0; kc < 2; ++kc) {
                bf16x8 hsf = *reinterpret_cast<const bf16x8*>(
                    &bufA[pt * 16 + l16][kc * 32 + quad * 8]);
                acc = __builtin_amdgcn_mfma_f32_16x16x32_bf16(afS[kc], hsf, acc, 0, 0, 0);
            }
            #pragma unroll
            for (int kc = 0; kc < 2; ++kc) {
                bf16x8 htf = *reinterpret_cast<const bf16x8*>(
                    &bufC[pt * 16 + l16][kc * 32 + quad * 8]);
                acc = __builtin_amdgcn_mfma_f32_16x16x32_bf16(afT[kc], htf, acc, 0, 0, 0);
            }
            const float zb[4] = {acc[0] + b4.x, acc[1] + b4.y, acc[2] + b4.z, acc[3] + b4.w};
            f32x4 h;
            #pragma unroll
            for (int r = 0; r < 4; ++r) {
                const float z = 1.0f / (1.0f + __expf(-zb[r]));
                h[r] = z * HSr[pt][r] + (1.0f - z) * HTr[pt][r];
            }
            t[pt] = h;
        }
    }
    __syncthreads();
    writeBuf(bufB, t, false);
    __syncthreads();

    gemm(bufB, 6, bh1, t);                  // H1 = relu(H@Wh1+b)
    __syncthreads();
    writeBuf(bufA, t, true);
    __syncthreads();

    gemm(bufA, 7, bh2, t);                  // out = X + H1@Wh2+b
    #pragma unroll
    for (int pt = 0; pt < 4; ++pt) {
        const long pos = p0 + pt * 16 + l16;
        const float4 xv = *reinterpret_cast<const float4*>(&X[pos * 64 + chBase]);
        float4 o;
        o.x = t[pt][0] + xv.x; o.y = t[pt][1] + xv.y;
        o.z = t[pt][2] + xv.z; o.w = t[pt][3] + xv.w;
        *reinterpret_cast<float4*>(&out[pos * 64 + chBase]) = o;
    }
}

// ---------------------------------------------------------------------------
extern "C" void kernel_launch(void* const* d_in, const int* in_sizes, int n_in,
                              void* d_out, int out_size, void* d_ws, size_t ws_size,
                              hipStream_t stream) {
    const float* X   = (const float*)d_in[0];
    const float* TLE = (const float*)d_in[1];
    const int* kpm   = (const int*)d_in[2];

    const float* sa_Wq = (const float*)d_in[3];  const float* sa_bq = (const float*)d_in[4];
    const float* sa_Wk = (const float*)d_in[5];  const float* sa_bk = (const float*)d_in[6];
    const float* sa_Wv = (const float*)d_in[7];  const float* sa_bv = (const float*)d_in[8];
    const float* sa_Wo1 = (const float*)d_in[9];  const float* sa_bo1 = (const float*)d_in[10];
    const float* sa_Wo2 = (const float*)d_in[11]; const float* sa_bo2 = (const float*)d_in[12];
    const float* ta_Wq = (const float*)d_in[13]; const float* ta_bq = (const float*)d_in[14];
    const float* ta_Wk = (const float*)d_in[15]; const float* ta_bk = (const float*)d_in[16];
    const float* ta_Wv = (const float*)d_in[17]; const float* ta_bv = (const float*)d_in[18];
    const float* ta_Wo1 = (const float*)d_in[19]; const float* ta_bo1 = (const float*)d_in[20];
    const float* ta_Wo2 = (const float*)d_in[21]; const float* ta_bo2 = (const float*)d_in[22];
    const float* g_Wxs = (const float*)d_in[23];
    const float* g_Wxt = (const float*)d_in[24]; const float* g_bxt = (const float*)d_in[25];
    const float* g_Wh1 = (const float*)d_in[26]; const float* g_bh1 = (const float*)d_in[27];
    const float* g_Wh2 = (const float*)d_in[28]; const float* g_bh2 = (const float*)d_in[29];

    unsigned short* wsp = (unsigned short*)d_ws;
    unsigned short* qs  = wsp + 0L * P64;   // [bt][h][n][8]
    unsigned short* ks  = wsp + 1L * P64;
    unsigned short* vs  = wsp + 2L * P64;
    unsigned short* qt  = wsp + 3L * P64;   // [b][n][t][64]
    unsigned short* kt  = wsp + 4L * P64;
    unsigned short* vt  = wsp + 5L * P64;
    unsigned short* HSb = wsp + 6L * P64;   // [pos][ch]
    unsigned short* HTb = wsp + 7L * P64;   // [pos][ch]
    unsigned short* Wt  = wsp + 8L * P64;            // 6*64*192 bf16
    unsigned short* Wt8 = Wt + 6 * 12288;            // 8*64*64 bf16

    float* out = (float*)d_out;

    hipLaunchKernelGGL(wprep_all, dim3(416), dim3(256), 0, stream,
                       sa_Wq, sa_Wk, sa_Wv, ta_Wq, ta_Wk, ta_Wv,
                       sa_Wo1, sa_Wo2, ta_Wo1, ta_Wo2, g_Wxs, g_Wxt, g_Wh1, g_Wh2,
                       Wt, Wt8);

    hipLaunchKernelGGL(proj_kernel, dim3(PTOT / 64), dim3(256), 0, stream,
                       X, TLE, Wt,
                       sa_bq, sa_bk, sa_bv, ta_bq, ta_bk, ta_bv,
                       qs, ks, vs, qt, kt, vt);

    hipLaunchKernelGGL(sattn_kernel, dim3(BB * TT * 8), dim3(128), 0, stream,
                       qs, ks, vs, HSb);

    hipLaunchKernelGGL(tattn_kernel, dim3(BB * NN), dim3(192), 0, stream,
                       qt, kt, vt, kpm, HTb);

    hipLaunchKernelGGL(epi_kernel, dim3(PTOT / 64), dim3(256), 0, stream,
                       X, HSb, HTb, Wt8,
                       sa_bo1, sa_bo2, ta_bo1, ta_bo2, g_bxt, g_bh1, g_bh2,
                       out);
}